// Round 9
// baseline (305.538 us; speedup 1.0000x reference)
//
#include <hip/hip_runtime.h>
#include <hip/hip_bf16.h>
#include <math.h>

// ---------------------------------------------------------------------------
// DistributedMoE forward, MI355X — R20: revert to best-known + gate fusion.
// R19 post-mortem: 1024-thr expALL clamped to 64 VGPR (LDS 56.8KB -> 2
// blocks/CU possible -> allocator targets 8 waves/SIMD) and spilled 58MB.
// expALL reverted to R18 body (40.6us, VGPR 120, proven). prep reverted to
// R14 version (best measured total config). NEW: gate_kernel deleted —
// fused into trunk via per-sample last-block pattern (store tfp ->
// __threadfence -> atomicAdd(cnt[b]); 8th block runs the gate MLP for
// sample b in its tail, same per-output summation order -> bit-identical).
// cnt[] zeroed in prep (don't trust the harness ws fill value).
//
// out (fp32): final[256,10] @0, balanced[256,8] @2560, D[256,8] @4608
// ---------------------------------------------------------------------------

#define BN_RS (1.0f / sqrtf(1.00001f))

typedef __attribute__((ext_vector_type(8))) short short8;
typedef __attribute__((ext_vector_type(4))) float floatx4;

static __device__ __forceinline__ ushort f2bf(float f) {
  unsigned u = __float_as_uint(f);
  unsigned r = (u + 0x7fffu + ((u >> 16) & 1u)) >> 16;   // RNE
  return (ushort)r;
}
static __device__ __forceinline__ float bf2f(ushort h) {
  return __uint_as_float((unsigned)h << 16);
}

// ws byte offsets
#define WS_TFP    0           // f32[256][8][32]
#define WS_TK     262144      // i32[512]
#define WS_W2H    264192      // bf16[9tap][32oc][32ic] hi   (18432 B)
#define WS_W2L    282624      // bf16[9tap][32oc][32ic] lo   (18432 B)
#define WS_EW2B   301056      // bf16[8][9tap][64oc][32ic]   (294912 B)
#define WS_EW3B   595968      // bf16[8][9tap][128oc][64ic]  (1179648 B)
#define WS_CNT    1775616     // i32[256] per-sample arrival counters

// =================== prep: weight transposes / splits ======================
// R14 version: 8 dest-consecutive ic per thread in regions B/C.
// grid 397: last block zeroes the per-sample counters.
__global__ __launch_bounds__(256) void prep_kernel(
    const float* __restrict__ tw2, const float* __restrict__ ew2,
    const float* __restrict__ ew3, ushort* __restrict__ w2h,
    ushort* __restrict__ w2l, ushort* __restrict__ ew2b,
    ushort* __restrict__ ew3b, int* __restrict__ cnt)
{
  const int j = blockIdx.x * 256 + threadIdx.x;
  if (j < 9216) {
    // trunk w2 hi/lo split: [tap][oc][ic]
    int tap = j >> 10, oc = (j >> 5) & 31, ic = j & 31;
    float v = tw2[oc*288 + ic*9 + tap];
    ushort h = f2bf(v);
    w2h[j] = h;
    w2l[j] = f2bf(v - bf2f(h));
  } else if (j < 27648) {
    const int jj = (j - 9216) * 8;           // dest [e][tap][oc64][ic32]
    int e = jj / 18432, r2 = jj % 18432;
    int tap = r2 / 2048, r3 = r2 % 2048;
    int oc = r3 / 32, ic0 = r3 % 32;
    const float* src = &ew2[e*18432 + oc*288 + ic0*9 + tap];
    short8 o;
    #pragma unroll
    for (int k = 0; k < 8; ++k) o[k] = (short)f2bf(src[k*9]);
    *(short8*)&ew2b[jj] = o;
  } else if (j < 101376) {
    const int jj = (j - 27648) * 8;          // dest [e][tap][oc128][ic64]
    int e = jj / 73728, r2 = jj % 73728;
    int tap = r2 / 8192, r3 = r2 % 8192;
    int oc = r3 / 64, ic0 = r3 % 64;
    const float* src = &ew3[e*73728 + oc*576 + ic0*9 + tap];
    short8 o;
    #pragma unroll
    for (int k = 0; k < 8; ++k) o[k] = (short)f2bf(src[k*9]);
    *(short8*)&ew3b[jj] = o;
  } else if (j < 101632) {
    cnt[j - 101376] = 0;                     // don't trust ws fill value
  }
}

// ====== fused trunk: conv1 fp32 -> hi/lo bf16 -> conv2 split-MFMA ==========
// grid 2048: b = blk>>3, rs = (blk>>1)&3 (8-row slab), ch = blk&1 (16-col).
// LDS 35392B -> 4 blocks/CU. Live VGPRs < 64 everywhere (R16-proven).
// Tail: per-sample last-block (atomic) runs the gate MLP for sample b.
__global__ __launch_bounds__(256) void trunk_kernel(
    const float* __restrict__ x, const float* __restrict__ tw1,
    const float* __restrict__ tg1, const float* __restrict__ tb1,
    const ushort* __restrict__ w2h, const ushort* __restrict__ w2l,
    const float* __restrict__ tg2, const float* __restrict__ tb2,
    const float* __restrict__ tfw, const float* __restrict__ tfb,
    const float* __restrict__ gw1, const float* __restrict__ gb1,
    const float* __restrict__ gw2, const float* __restrict__ gb2,
    float* __restrict__ tfp, float* __restrict__ outBal,
    int* __restrict__ tk, int* __restrict__ cnt)
{
  __shared__ __align__(16) ushort smu[17696];
  __shared__ int sOld;
  float* smf = (float*)&smu[14400];
  const int t = threadIdx.x, blk = blockIdx.x;
  const int b = blk >> 3, rs = (blk >> 1) & 3, ch = blk & 1;
  const int r0 = rs * 8, c0 = ch * 16;

  // zero IMG hi+lo (halo ring + invalid rows/cols must be 0)
  {
    uint4 z = {0, 0, 0, 0};
    for (int j = t; j < 1800; j += 256) ((uint4*)smu)[j] = z;
  }
  // stage x slab: rows r0-2..r0+9 (12), cols c0-2..c0+17 (20), 3 ic
  for (int j = t; j < 720; j += 256) {
    int ic = j / 240, rem = j % 240, rr = rem / 20, c = rem % 20;
    int gy = r0 - 2 + rr, gx = c0 - 2 + c;
    float v = 0.f;
    if (gy >= 0 && gy < 32 && gx >= 0 && gx < 32)
      v = x[b*3072 + ic*1024 + gy*32 + gx];
    smf[j] = v;
  }
  // stage w1 transposed [ic][k][oc]
  for (int j = t; j < 864; j += 256) {
    int oc = j / 27, r = j % 27, ic = r / 9, k = r % 9;
    smf[720 + ic*288 + k*32 + oc] = tw1[j];
  }
  if (t < 32) { smf[1584 + t] = tg1[t]*BN_RS; smf[1584 + 32 + t] = tb1[t]; }
  __syncthreads();

  // ---- conv1 fp32: item = oc(32) x row(10) = 320 items, 2 passes ----
  for (int it = 0; it < 2; ++it) {
    const int item = it*256 + t;
    if (item < 320) {
      const int oc = item & 31, rr = item >> 5;
      const int grow = r0 - 1 + rr;              // conv1 output global row
      if (grow >= 0 && grow < 32) {
        float acc[18];
        #pragma unroll
        for (int c = 0; c < 18; ++c) acc[c] = 0.f;
        #pragma unroll 1
        for (int ic = 0; ic < 3; ++ic) {
          #pragma unroll 1
          for (int ky = 0; ky < 3; ++ky) {
            float wk[3];
            #pragma unroll
            for (int kx = 0; kx < 3; ++kx)
              wk[kx] = smf[720 + ic*288 + (ky*3 + kx)*32 + oc];
            const float* srow = &smf[ic*240 + (rr + ky)*20];
            float v[20];
            #pragma unroll
            for (int j4 = 0; j4 < 5; ++j4) {
              float4 q = *(const float4*)&srow[4*j4];
              v[4*j4] = q.x; v[4*j4+1] = q.y; v[4*j4+2] = q.z; v[4*j4+3] = q.w;
            }
            #pragma unroll
            for (int kx = 0; kx < 3; ++kx)
              #pragma unroll
              for (int c = 0; c < 18; ++c)
                acc[c] = fmaf(wk[kx], v[c+kx], acc[c]);
          }
        }
        // bn+relu, hi/lo split, ushort stores into IMG [row][col][40ch]
        const float s = smf[1584 + oc], bo = smf[1584 + 32 + oc];
        #pragma unroll
        for (int c = 0; c < 18; ++c) {
          const int gcol = c0 - 1 + c;
          float va = 0.f;
          if (gcol >= 0 && gcol < 32)
            va = fmaxf(fmaf(acc[c], s, bo), 0.f);
          ushort h = f2bf(va);
          ushort lo = f2bf(va - bf2f(h));
          const int ui = (rr*18 + c)*40 + oc;
          smu[ui] = h;
          smu[7200 + ui] = lo;
        }
      }
    }
  }
  __syncthreads();

  // ---- conv2 split-MFMA: wave = (yh row-half, nt oc-tile); 4-row acc ----
  const int w4 = t >> 6, l = t & 63, col = l & 15, quad = l >> 4;
  const int nt = w4 & 1, yh = w4 >> 1;
  const int oc = nt*16 + col;
  const float s2 = tg2[oc]*BN_RS, bo2 = tb2[oc];   // hoisted scalar prefetch
  floatx4 acc2[4];
  #pragma unroll
  for (int y = 0; y < 4; ++y)
    #pragma unroll
    for (int i = 0; i < 4; ++i) acc2[y][i] = 0.f;

  #pragma unroll
  for (int dx = 0; dx < 3; ++dx) {
    #pragma unroll
    for (int dy = 0; dy < 3; ++dy) {
      const int wi = (dy*3 + dx)*1024 + (nt*16 + col)*32 + quad*8;
      short8 bh = *(const short8*)&w2h[wi];
      short8 bl = *(const short8*)&w2l[wi];
      #pragma unroll
      for (int y = 0; y < 4; ++y) {
        const int idx = ((yh*4 + y + dy)*18 + col + dx)*40 + quad*8;
        short8 ah = *(const short8*)&smu[idx];
        short8 al = *(const short8*)&smu[7200 + idx];
        acc2[y] = __builtin_amdgcn_mfma_f32_16x16x32_bf16(ah, bh, acc2[y], 0, 0, 0);
        acc2[y] = __builtin_amdgcn_mfma_f32_16x16x32_bf16(ah, bl, acc2[y], 0, 0, 0);
        acc2[y] = __builtin_amdgcn_mfma_f32_16x16x32_bf16(al, bh, acc2[y], 0, 0, 0);
      }
    }
  }

  // ---- epilogue: bn2+relu+2x2 maxpool + quadrant partial sum -> tfp ----
  {
    float psum = 0.f;
    #pragma unroll
    for (int yp = 0; yp < 2; ++yp)
      #pragma unroll
      for (int i2 = 0; i2 < 2; ++i2) {
        float v00 = fmaxf(fmaf(acc2[2*yp][2*i2],     s2, bo2), 0.f);
        float v01 = fmaxf(fmaf(acc2[2*yp][2*i2+1],   s2, bo2), 0.f);
        float v10 = fmaxf(fmaf(acc2[2*yp+1][2*i2],   s2, bo2), 0.f);
        float v11 = fmaxf(fmaf(acc2[2*yp+1][2*i2+1], s2, bo2), 0.f);
        psum += fmaxf(fmaxf(v00, v01), fmaxf(v10, v11));
      }
    psum += __shfl_xor(psum, 16);
    psum += __shfl_xor(psum, 32);
    if (yh == 1 && quad == 0) smf[nt*32 + col] = psum;   // XS region is dead
    __syncthreads();
    if (yh == 0 && quad == 0) {
      float tot = psum + smf[nt*32 + col];
      tfp[b*256 + (rs*2 + ch)*32 + oc] = tot;
    }
  }

  // ---- fused gate: per-sample last-block runs the gate MLP (G12/G16) ----
  __threadfence();                    // make tfp chunk device-visible
  __syncthreads();
  if (t == 0) sOld = atomicAdd(&cnt[b], 1);
  __syncthreads();
  if (sOld == 7) {
    float* feat = &smf[64];           // 128 f32 (XS region is dead)
    float* rf   = &smf[192];          // 64
    float* g1s  = &smf[256];          // 32
    float* bal  = &smf[288];          // 8
    if (t < 128) {
      const int f = t;
      const int ocf = f >> 2, qy = (f >> 1) & 1, qx = f & 1;
      feat[f] = (tfp[b*256 + (4*qy + qx)*32 + ocf] +
                 tfp[b*256 + (4*qy + 2 + qx)*32 + ocf]) * (1.f/64.f);
    }
    __syncthreads();
    if (t < 64) {
      float a = tfb[t];
      const float4* wp = (const float4*)&tfw[t*128];
      #pragma unroll 8
      for (int i4 = 0; i4 < 32; ++i4) {
        float4 wv = wp[i4];
        a = fmaf(wv.x, feat[4*i4], a);   a = fmaf(wv.y, feat[4*i4+1], a);
        a = fmaf(wv.z, feat[4*i4+2], a); a = fmaf(wv.w, feat[4*i4+3], a);
      }
      rf[t] = fmaxf(a, 0.f);
    }
    __syncthreads();
    if (t < 32) {
      float a = gb1[t];
      const float4* wp = (const float4*)&gw1[t*64];
      #pragma unroll
      for (int i4 = 0; i4 < 16; ++i4) {
        float4 wv = wp[i4];
        a = fmaf(wv.x, rf[4*i4], a);   a = fmaf(wv.y, rf[4*i4+1], a);
        a = fmaf(wv.z, rf[4*i4+2], a); a = fmaf(wv.w, rf[4*i4+3], a);
      }
      g1s[t] = fmaxf(a, 0.f);
    }
    __syncthreads();
    if (t < 8) {
      float a = gb2[t];
      const float4* wp = (const float4*)&gw2[t*32];
      #pragma unroll
      for (int i4 = 0; i4 < 8; ++i4) {
        float4 wv = wp[i4];
        a = fmaf(wv.x, g1s[4*i4], a);   a = fmaf(wv.y, g1s[4*i4+1], a);
        a = fmaf(wv.z, g1s[4*i4+2], a); a = fmaf(wv.w, g1s[4*i4+3], a);
      }
      const float v = a - 0.25f;   // boost=0, -LOAD_PEN*usage = -0.25
      bal[t] = v;
      outBal[b*8 + t] = v;
    }
    __syncthreads();
    if (t == 0) {
      int t0 = 0; float b0 = bal[0];
      #pragma unroll
      for (int e2 = 1; e2 < 8; ++e2) if (bal[e2] > b0) { b0 = bal[e2]; t0 = e2; }
      int t1 = -1; float b1 = -3.4e38f;
      #pragma unroll
      for (int e2 = 0; e2 < 8; ++e2) if (e2 != t0 && bal[e2] > b1) { b1 = bal[e2]; t1 = e2; }
      tk[b*2] = t0; tk[b*2 + 1] = t1;
    }
  }
}

// ========== expALL: scan + conv1 + conv2(MFMA) + conv3(MFMA) + FC ==========
// grid 256 = one block/sample, 512 thr, __launch_bounds__(512,2).
// R18 body (40.6us, VGPR 120, WRITE 24KB — proven).
#define XA_IMG  0
#define XA_FEAT 3600
#define XA_SFF  3728
#define XA_SGG  3856
#define XA_XF   9040
#define XA_W1F  12508
#define XA_BN1F 13372
#define XA_SC   9040      // FC partial-sum scratch (512 f32), after conv3
__global__ __launch_bounds__(512, 2) void expALL_kernel(
    const float* __restrict__ x, const int* __restrict__ tk,
    const float* __restrict__ ew1, const float* __restrict__ eg1,
    const float* __restrict__ eb1, const ushort* __restrict__ ew2b,
    const float* __restrict__ eg2, const float* __restrict__ eb2,
    const ushort* __restrict__ ew3b, const float* __restrict__ eg3,
    const float* __restrict__ eb3, const float* __restrict__ efw,
    const float* __restrict__ efb, const float* __restrict__ cw1,
    const float* __restrict__ cb1, const float* __restrict__ cw2,
    const float* __restrict__ cb2, float* __restrict__ outF,
    float* __restrict__ outD)
{
  __shared__ __align__(16) ushort smu[27296];
  __shared__ int stk[512];
  __shared__ int sch;
  float* smf = (float*)smu;
  const int t = threadIdx.x, b = blockIdx.x;
  const int w8 = t >> 6, l = t & 63;
  const int col = l & 15, quad = l >> 4;

  // ---- 1) stage tk, then scan (t0, packed u64) || zero IMG + stage x ----
  stk[t] = tk[t];
  __syncthreads();
  if (t == 0) {
    unsigned long long Lp = 0ull;
    int chv = 0;
    for (int i = 0; i <= b; ++i) {
      const int a = stk[2*i], c = stk[2*i+1];
      const int la = (int)((Lp >> (a*8)) & 0xFFull);
      const int lc = (int)((Lp >> (c*8)) & 0xFFull);
      chv = (la < 48) ? a : ((lc < 48) ? c : ((la <= lc) ? a : c));
      Lp += 1ull << (chv*8);
    }
    sch = chv;
  } else {
    uint4 z; z.x = 0; z.y = 0; z.z = 0; z.w = 0;
    for (int j = t-1; j < 1620; j += 511) ((uint4*)smu)[j] = z;
    for (int j = t-1; j < 3468; j += 511) {
      int ic = j / 1156, rem = j % 1156, p = rem / 34, cpd = rem % 34;
      int gy = p - 1, gx = cpd - 1;
      float v = 0.f;
      if (gy >= 0 && gy < 32 && gx >= 0 && gx < 32) v = x[b*3072 + ic*1024 + gy*32 + gx];
      smf[XA_XF + j] = v;
    }
  }
  __syncthreads();
  const int e = sch;
  if (t < 8) outD[b*8 + t] = (t == e) ? 1.f : 0.f;

  // ---- 2) conv2 B-fragments -> VGPRs ----
  const int ntile = w8 & 3, mhalf = w8 >> 2;   // conv2 wave mapping
  short8 w2f[9];
  {
    const int oc2 = ntile*16 + col;
    #pragma unroll
    for (int tap = 0; tap < 9; ++tap)
      w2f[tap] = *(const short8*)&ew2b[(e*9 + tap)*2048 + oc2*32 + quad*8];
  }

  // stage w1t [ic][k][oc], bn1
  for (int j = t; j < 864; j += 512) {
    int oc = j / 27, r = j % 27, ic = r / 9, k = r % 9;
    smf[XA_W1F + ic*288 + k*32 + oc] = ew1[e*864 + j];
  }
  if (t < 32) { smf[XA_BN1F + t] = eg1[e*32 + t]*BN_RS; smf[XA_BN1F + 32 + t] = eb1[e*32 + t]; }
  __syncthreads();

  // ---- 3) conv1 fp32: 16 groups x 2 oc x 32 cols; rolled slab/ic loops ---
  {
    const int g = t >> 5, c = t & 31;        // g in 0..15 (2 oc each)
    #pragma unroll 1
    for (int rs = 0; rs < 4; ++rs) {
      const int r0 = rs * 8;
      float acc[2][8];
      #pragma unroll
      for (int o = 0; o < 2; ++o)
        #pragma unroll
        for (int r = 0; r < 8; ++r) acc[o][r] = 0.f;
      #pragma unroll 1
      for (int ic = 0; ic < 3; ++ic) {
        float w[2][9];
        #pragma unroll
        for (int k = 0; k < 9; ++k) {
          float2 wv = *(const float2*)&smf[XA_W1F + ic*288 + k*32 + 2*g];
          w[0][k] = wv.x; w[1][k] = wv.y;
        }
        const float* src = &smf[XA_XF + ic*1156 + r0*34 + c];
        #pragma unroll
        for (int rr = 0; rr < 10; ++rr) {
          const float i0 = src[rr*34], i1 = src[rr*34 + 1], i2 = src[rr*34 + 2];
          #pragma unroll
          for (int dr = 0; dr < 3; ++dr) {
            const int r = rr - dr;
            if (r < 0 || r > 7) continue;
            #pragma unroll
            for (int o = 0; o < 2; ++o) {
              acc[o][r] = fmaf(w[o][dr*3+0], i0, acc[o][r]);
              acc[o][r] = fmaf(w[o][dr*3+1], i1, acc[o][r]);
              acc[o][r] = fmaf(w[o][dr*3+2], i2, acc[o][r]);
            }
          }
        }
      }
      #pragma unroll
      for (int o = 0; o < 2; ++o) {
        const int oc = 2*g + o;
        const float s = smf[XA_BN1F + oc], bo = smf[XA_BN1F + 32 + oc];
        float m[4];
        #pragma unroll
        for (int pr = 0; pr < 4; ++pr) {
          float v0 = fmaxf(fmaf(acc[o][2*pr],   s, bo), 0.f);
          float v1 = fmaxf(fmaf(acc[o][2*pr+1], s, bo), 0.f);
          m[pr] = fmaxf(v0, v1);
        }
        #pragma unroll
        for (int pr = 0; pr < 4; ++pr) {
          float nb = __shfl_xor(m[pr], 1);
          m[pr] = fmaxf(m[pr], nb);
        }
        if (!(c & 1)) {
          const int pc = c >> 1;
          #pragma unroll
          for (int pr = 0; pr < 4; ++pr)
            smu[XA_IMG + ((rs*4 + pr + 1)*18 + (pc + 1))*40 + oc] = f2bf(m[pr]);
        }
      }
    }
  }
  __syncthreads();

  // ---- 4) conv3 B-fragments -> VGPRs ----
  const int oc3 = w8*16 + col;
  short8 w3f[9][2];
  #pragma unroll
  for (int tap = 0; tap < 9; ++tap)
    #pragma unroll
    for (int ks = 0; ks < 2; ++ks)
      w3f[tap][ks] = *(const short8*)&ew3b[(e*9 + tap)*8192 + oc3*64 + ks*32 + quad*8];

  // ---- 4b) scalar prefetches only (wide arrays spill — R17) ----
  const int poc2 = ntile*16 + col;
  const float s2p = eg2[e*64 + poc2]*BN_RS, b2p = eb2[e*64 + poc2];
  const float s3p = eg3[e*128 + oc3]*BN_RS, b3p = eb3[e*128 + oc3];
  const int fcout = t & 127, fcpart = t >> 7;
  const float efbp = (fcpart == 0) ? efb[e*128 + fcout] : 0.f;

  // ---- 5) conv2 MFMA: straight-line, no barriers (B in regs) ----
  {
    floatx4 acc[8];
    #pragma unroll
    for (int mt = 0; mt < 8; ++mt)
      #pragma unroll
      for (int i = 0; i < 4; ++i) acc[mt][i] = 0.f;

    #pragma unroll
    for (int tap = 0; tap < 9; ++tap) {
      const int dy = tap / 3, dx = tap % 3;
      #pragma unroll
      for (int mtl = 0; mtl < 8; ++mtl) {
        const int mt = mhalf*8 + mtl;
        short8 afr = *(const short8*)
            &smu[XA_IMG + ((mt + dy)*18 + col + dx)*40 + quad*8];
        acc[mtl] = __builtin_amdgcn_mfma_f32_16x16x32_bf16(afr, w2f[tap], acc[mtl], 0, 0, 0);
      }
    }
    __syncthreads();   // all waves done reading IMG before P2T overlay

    // P2T borders + pooled interior (overlays dead IMG)
    {
      uint4 z; z.x = 0; z.y = 0; z.z = 0; z.w = 0;
      for (int j = t; j < 288; j += 512) {
        int slot = j >> 3, ofs = (j & 7) * 8, row, cl;
        if (slot < 10)      { row = 0; cl = slot; }
        else if (slot < 20) { row = 9; cl = slot - 10; }
        else if (slot < 28) { row = 1 + (slot - 20); cl = 0; }
        else                { row = 1 + (slot - 28); cl = 9; }
        *(uint4*)&smu[(row*10 + cl)*72 + ofs] = z;
      }
    }
    #pragma unroll
    for (int mtpl = 0; mtpl < 4; ++mtpl) {
      const int mtp = mhalf*4 + mtpl;
      float a00 = fmaxf(fmaf(acc[2*mtpl][0],   s2p, b2p), 0.f);
      float a01 = fmaxf(fmaf(acc[2*mtpl][1],   s2p, b2p), 0.f);
      float a02 = fmaxf(fmaf(acc[2*mtpl][2],   s2p, b2p), 0.f);
      float a03 = fmaxf(fmaf(acc[2*mtpl][3],   s2p, b2p), 0.f);
      float a10 = fmaxf(fmaf(acc[2*mtpl+1][0], s2p, b2p), 0.f);
      float a11 = fmaxf(fmaf(acc[2*mtpl+1][1], s2p, b2p), 0.f);
      float a12 = fmaxf(fmaf(acc[2*mtpl+1][2], s2p, b2p), 0.f);
      float a13 = fmaxf(fmaf(acc[2*mtpl+1][3], s2p, b2p), 0.f);
      float p0 = fmaxf(fmaxf(a00, a01), fmaxf(a10, a11));
      float p1 = fmaxf(fmaxf(a02, a03), fmaxf(a12, a13));
      smu[((mtp + 1)*10 + (quad*2 + 1))*72 + poc2] = f2bf(p0);
      smu[((mtp + 1)*10 + (quad*2 + 2))*72 + poc2] = f2bf(p1);
    }
  }
  __syncthreads();

  // ---- 6) prefetch FC layer-1 row into regs (hide under conv3) ----
  float4 efr[8];
  {
    const float4* wp = (const float4*)&efw[e*16384 + fcout*128 + fcpart*32];
    #pragma unroll
    for (int i4 = 0; i4 < 8; ++i4) efr[i4] = wp[i4];
  }

  // ---- 7) conv3 MFMA: straight-line (B in regs, A from P2T LDS) ----
  {
    floatx4 acc[4];
    #pragma unroll
    for (int mt = 0; mt < 4; ++mt)
      #pragma unroll
      for (int i = 0; i < 4; ++i) acc[mt][i] = 0.f;

    #pragma unroll
    for (int tap = 0; tap < 9; ++tap) {
      const int dy = tap / 3, dx = tap % 3;
      #pragma unroll
      for (int ks = 0; ks < 2; ++ks) {
        #pragma unroll
        for (int mt = 0; mt < 4; ++mt) {
          const int m = mt*16 + col;
          const int y = m >> 3, xx = m & 7;
          short8 afr = *(const short8*)
              &smu[((y + dy)*10 + (xx + dx))*72 + ks*32 + quad*8];
          acc[mt] = __builtin_amdgcn_mfma_f32_16x16x32_bf16(afr, w3f[tap][ks], acc[mt], 0, 0, 0);
        }
      }
    }

    // epilogue: bn + relu + GAP -> feat in LDS
    {
      float gsum = 0.f;
      #pragma unroll
      for (int mt = 0; mt < 4; ++mt)
        #pragma unroll
        for (int i = 0; i < 4; ++i)
          gsum += fmaxf(fmaf(acc[mt][i], s3p, b3p), 0.f);
      gsum += __shfl_xor(gsum, 16);
      gsum += __shfl_xor(gsum, 32);
      if (quad == 0) smf[XA_FEAT + oc3] = gsum * (1.f/64.f);
    }
  }
  __syncthreads();

  // ---- 8) FC chain, 4-way dot split via LDS scratch ----
  {
    float a = efbp;
    #pragma unroll
    for (int i4 = 0; i4 < 8; ++i4) {
      float4 wv = efr[i4];
      const int base = XA_FEAT + fcpart*32 + 4*i4;
      a = fmaf(wv.x, smf[base], a);     a = fmaf(wv.y, smf[base + 1], a);
      a = fmaf(wv.z, smf[base + 2], a); a = fmaf(wv.w, smf[base + 3], a);
    }
    smf[XA_SC + fcpart*128 + fcout] = a;
  }
  __syncthreads();
  if (t < 128)
    smf[XA_SFF + t] = fmaxf(smf[XA_SC + t] + smf[XA_SC + 128 + t] +
                            smf[XA_SC + 256 + t] + smf[XA_SC + 384 + t], 0.f);
  __syncthreads();
  if (t < 256) {
    const int out = t & 63, part = t >> 6;      // part 0..3
    float a = (part == 0) ? cb1[e*64 + out] : 0.f;
    const float4* wp = (const float4*)&cw1[e*8192 + out*128 + part*32];
    #pragma unroll
    for (int i4 = 0; i4 < 8; ++i4) {
      float4 wv = wp[i4];
      const int base = XA_SFF + part*32 + 4*i4;
      a = fmaf(wv.x, smf[base], a);     a = fmaf(wv.y, smf[base + 1], a);
      a = fmaf(wv.z, smf[base + 2], a); a = fmaf(wv.w, smf[base + 3], a);
    }
    smf[XA_SC + part*64 + out] = a;
  }
  __syncthreads();
  if (t < 64)
    smf[XA_SGG + t] = fmaxf(smf[XA_SC + t] + smf[XA_SC + 64 + t] +
                            smf[XA_SC + 128 + t] + smf[XA_SC + 192 + t], 0.f);
  __syncthreads();
  if (t < 10) {
    float a = cb2[e*10 + t];
    const float4* wp = (const float4*)&cw2[e*640 + t*64];
    #pragma unroll
    for (int i4 = 0; i4 < 16; ++i4) {
      float4 wv = wp[i4];
      a = fmaf(wv.x, smf[XA_SGG + 4*i4],     a);
      a = fmaf(wv.y, smf[XA_SGG + 4*i4 + 1], a);
      a = fmaf(wv.z, smf[XA_SGG + 4*i4 + 2], a);
      a = fmaf(wv.w, smf[XA_SGG + 4*i4 + 3], a);
    }
    outF[b*10 + t] = a;   // routing weight is exactly 1.0 for the chosen expert
  }
}

// ================================ host =====================================
extern "C" void kernel_launch(void* const* d_in, const int* in_sizes, int n_in,
                              void* d_out, int out_size, void* d_ws, size_t ws_size,
                              hipStream_t stream)
{
  const float* x   = (const float*)d_in[0];
  const float* tw1 = (const float*)d_in[1];
  const float* tg1 = (const float*)d_in[2];
  const float* tb1 = (const float*)d_in[3];
  const float* tw2 = (const float*)d_in[4];
  const float* tg2 = (const float*)d_in[5];
  const float* tb2 = (const float*)d_in[6];
  const float* tfw = (const float*)d_in[7];
  const float* tfb = (const float*)d_in[8];
  const float* gw1 = (const float*)d_in[9];
  const float* gb1 = (const float*)d_in[10];
  const float* gw2 = (const float*)d_in[11];
  const float* gb2 = (const float*)d_in[12];
  const float* ew1 = (const float*)d_in[13];
  const float* eg1 = (const float*)d_in[14];
  const float* eb1 = (const float*)d_in[15];
  const float* ew2 = (const float*)d_in[16];
  const float* eg2 = (const float*)d_in[17];
  const float* eb2 = (const float*)d_in[18];
  const float* ew3 = (const float*)d_in[19];
  const float* eg3 = (const float*)d_in[20];
  const float* eb3 = (const float*)d_in[21];
  const float* efw = (const float*)d_in[22];
  const float* efb = (const float*)d_in[23];
  const float* cw1 = (const float*)d_in[24];
  const float* cb1 = (const float*)d_in[25];
  const float* cw2 = (const float*)d_in[26];
  const float* cb2 = (const float*)d_in[27];

  float*  out  = (float*)d_out;
  char*   ws   = (char*)d_ws;
  float*  tfp  = (float*)(ws + WS_TFP);
  int*    tk   = (int*)(ws + WS_TK);
  ushort* w2h  = (ushort*)(ws + WS_W2H);
  ushort* w2l  = (ushort*)(ws + WS_W2L);
  ushort* ew2b = (ushort*)(ws + WS_EW2B);
  ushort* ew3b = (ushort*)(ws + WS_EW3B);
  int*    cnt  = (int*)(ws + WS_CNT);

  prep_kernel<<<397, 256, 0, stream>>>(tw2, ew2, ew3, w2h, w2l, ew2b, ew3b, cnt);
  trunk_kernel<<<2048, 256, 0, stream>>>(x, tw1, tg1, tb1, w2h, w2l, tg2, tb2,
                                         tfw, tfb, gw1, gb1, gw2, gb2,
                                         tfp, out + 2560, tk, cnt);
  expALL_kernel<<<256, 512, 0, stream>>>(x, tk, ew1, eg1, eb1, ew2b, eg2, eb2,
                                         ew3b, eg3, eb3, efw, efb, cw1, cb1,
                                         cw2, cb2, out, out + 4608);
}

// Round 10
// 181.944 us; speedup vs baseline: 1.6793x; 1.6793x over previous
//
#include <hip/hip_runtime.h>
#include <hip/hip_bf16.h>
#include <math.h>

// ---------------------------------------------------------------------------
// DistributedMoE forward, MI355X — R21: revert to R16 (best verified, 182.8us).
// R20 post-mortem: fusing gate into trunk via __threadfence+atomicAdd made
// trunk 167us (HBM 0.4%, VALU 8.5%) — per-block device-scope release fences
// (L2 writeback + vmcnt drain) across 2048 blocks serialized on the XCD L2
// and the hot cnt line, costing ~150us to save ~5. Reverted.
// Search summary: expALL pinned at ~40.6us (cold-load hoists null, code-size
// null, wave-scaling blocked by 64-VGPR allocator clamp, fusion negative);
// floor = fill 40.4 + expALL 40.6 + trunk <40 + prep/gate/gaps.
//
// out (fp32): final[256,10] @0, balanced[256,8] @2560, D[256,8] @4608
// ---------------------------------------------------------------------------

#define BN_RS (1.0f / sqrtf(1.00001f))

typedef __attribute__((ext_vector_type(8))) short short8;
typedef __attribute__((ext_vector_type(4))) float floatx4;

static __device__ __forceinline__ ushort f2bf(float f) {
  unsigned u = __float_as_uint(f);
  unsigned r = (u + 0x7fffu + ((u >> 16) & 1u)) >> 16;   // RNE
  return (ushort)r;
}
static __device__ __forceinline__ float bf2f(ushort h) {
  return __uint_as_float((unsigned)h << 16);
}

// ws byte offsets
#define WS_TFP    0           // f32[256][8][32]
#define WS_TK     262144      // i32[512]
#define WS_W2H    264192      // bf16[9tap][32oc][32ic] hi   (18432 B)
#define WS_W2L    282624      // bf16[9tap][32oc][32ic] lo   (18432 B)
#define WS_EW2B   301056      // bf16[8][9tap][64oc][32ic]   (294912 B)
#define WS_EW3B   595968      // bf16[8][9tap][128oc][64ic]  (1179648 B)

// =================== prep: weight transposes / splits ======================
// 8 dest-consecutive ic per thread in regions B/C: 8 strided loads +
// one coalesced b128 store. 101376 threads total (396 blocks).
__global__ __launch_bounds__(256) void prep_kernel(
    const float* __restrict__ tw2, const float* __restrict__ ew2,
    const float* __restrict__ ew3, ushort* __restrict__ w2h,
    ushort* __restrict__ w2l, ushort* __restrict__ ew2b,
    ushort* __restrict__ ew3b)
{
  const int j = blockIdx.x * 256 + threadIdx.x;
  if (j < 9216) {
    // trunk w2 hi/lo split: [tap][oc][ic]
    int tap = j >> 10, oc = (j >> 5) & 31, ic = j & 31;
    float v = tw2[oc*288 + ic*9 + tap];
    ushort h = f2bf(v);
    w2h[j] = h;
    w2l[j] = f2bf(v - bf2f(h));
  } else if (j < 27648) {
    const int jj = (j - 9216) * 8;           // dest [e][tap][oc64][ic32]
    int e = jj / 18432, r2 = jj % 18432;
    int tap = r2 / 2048, r3 = r2 % 2048;
    int oc = r3 / 32, ic0 = r3 % 32;
    const float* src = &ew2[e*18432 + oc*288 + ic0*9 + tap];
    short8 o;
    #pragma unroll
    for (int k = 0; k < 8; ++k) o[k] = (short)f2bf(src[k*9]);
    *(short8*)&ew2b[jj] = o;
  } else if (j < 101376) {
    const int jj = (j - 27648) * 8;          // dest [e][tap][oc128][ic64]
    int e = jj / 73728, r2 = jj % 73728;
    int tap = r2 / 8192, r3 = r2 % 8192;
    int oc = r3 / 64, ic0 = r3 % 64;
    const float* src = &ew3[e*73728 + oc*576 + ic0*9 + tap];
    short8 o;
    #pragma unroll
    for (int k = 0; k < 8; ++k) o[k] = (short)f2bf(src[k*9]);
    *(short8*)&ew3b[jj] = o;
  }
}

// ====== fused trunk: conv1 fp32 -> hi/lo bf16 -> conv2 split-MFMA ==========
// grid 2048: b = blk>>3, rs = (blk>>1)&3 (8-row slab), ch = blk&1 (16-col).
// LDS 35392B -> 4 blocks/CU. Live VGPRs kept <64 everywhere (R16-proven):
// conv1 one oc per item (acc[18]+v[20]+wk[3], unroll-1 outer loops);
// conv2 A-fragments read inline per MFMA.
__global__ __launch_bounds__(256) void trunk_kernel(
    const float* __restrict__ x, const float* __restrict__ tw1,
    const float* __restrict__ tg1, const float* __restrict__ tb1,
    const ushort* __restrict__ w2h, const ushort* __restrict__ w2l,
    const float* __restrict__ tg2, const float* __restrict__ tb2,
    float* __restrict__ tfp)
{
  __shared__ __align__(16) ushort smu[17696];
  float* smf = (float*)&smu[14400];
  const int t = threadIdx.x, blk = blockIdx.x;
  const int b = blk >> 3, rs = (blk >> 1) & 3, ch = blk & 1;
  const int r0 = rs * 8, c0 = ch * 16;

  // zero IMG hi+lo (halo ring + invalid rows/cols must be 0)
  {
    uint4 z = {0, 0, 0, 0};
    for (int j = t; j < 1800; j += 256) ((uint4*)smu)[j] = z;
  }
  // stage x slab: rows r0-2..r0+9 (12), cols c0-2..c0+17 (20), 3 ic
  for (int j = t; j < 720; j += 256) {
    int ic = j / 240, rem = j % 240, rr = rem / 20, c = rem % 20;
    int gy = r0 - 2 + rr, gx = c0 - 2 + c;
    float v = 0.f;
    if (gy >= 0 && gy < 32 && gx >= 0 && gx < 32)
      v = x[b*3072 + ic*1024 + gy*32 + gx];
    smf[j] = v;
  }
  // stage w1 transposed [ic][k][oc]
  for (int j = t; j < 864; j += 256) {
    int oc = j / 27, r = j % 27, ic = r / 9, k = r % 9;
    smf[720 + ic*288 + k*32 + oc] = tw1[j];
  }
  if (t < 32) { smf[1584 + t] = tg1[t]*BN_RS; smf[1584 + 32 + t] = tb1[t]; }
  __syncthreads();

  // ---- conv1 fp32: item = oc(32) x row(10) = 320 items, 2 passes ----
  // acc[18] + v[20] + wk[3], unroll-1 outer loops: ~45 live VGPRs.
  for (int it = 0; it < 2; ++it) {
    const int item = it*256 + t;
    if (item < 320) {
      const int oc = item & 31, rr = item >> 5;
      const int grow = r0 - 1 + rr;              // conv1 output global row
      if (grow >= 0 && grow < 32) {
        float acc[18];
        #pragma unroll
        for (int c = 0; c < 18; ++c) acc[c] = 0.f;
        #pragma unroll 1
        for (int ic = 0; ic < 3; ++ic) {
          #pragma unroll 1
          for (int ky = 0; ky < 3; ++ky) {
            float wk[3];
            #pragma unroll
            for (int kx = 0; kx < 3; ++kx)
              wk[kx] = smf[720 + ic*288 + (ky*3 + kx)*32 + oc];
            const float* srow = &smf[ic*240 + (rr + ky)*20];
            float v[20];
            #pragma unroll
            for (int j4 = 0; j4 < 5; ++j4) {
              float4 q = *(const float4*)&srow[4*j4];
              v[4*j4] = q.x; v[4*j4+1] = q.y; v[4*j4+2] = q.z; v[4*j4+3] = q.w;
            }
            #pragma unroll
            for (int kx = 0; kx < 3; ++kx)
              #pragma unroll
              for (int c = 0; c < 18; ++c)
                acc[c] = fmaf(wk[kx], v[c+kx], acc[c]);
          }
        }
        // bn+relu, hi/lo split, ushort stores into IMG [row][col][40ch]
        const float s = smf[1584 + oc], bo = smf[1584 + 32 + oc];
        #pragma unroll
        for (int c = 0; c < 18; ++c) {
          const int gcol = c0 - 1 + c;
          float va = 0.f;
          if (gcol >= 0 && gcol < 32)
            va = fmaxf(fmaf(acc[c], s, bo), 0.f);
          ushort h = f2bf(va);
          ushort lo = f2bf(va - bf2f(h));
          const int ui = (rr*18 + c)*40 + oc;
          smu[ui] = h;
          smu[7200 + ui] = lo;
        }
      }
    }
  }
  __syncthreads();

  // ---- conv2 split-MFMA: wave = (yh row-half, nt oc-tile); 4-row acc ----
  // A-fragments read inline per MFMA (expALL's proven low-pressure pattern).
  const int w4 = t >> 6, l = t & 63, col = l & 15, quad = l >> 4;
  const int nt = w4 & 1, yh = w4 >> 1;
  floatx4 acc2[4];
  #pragma unroll
  for (int y = 0; y < 4; ++y)
    #pragma unroll
    for (int i = 0; i < 4; ++i) acc2[y][i] = 0.f;

  #pragma unroll
  for (int dx = 0; dx < 3; ++dx) {
    #pragma unroll
    for (int dy = 0; dy < 3; ++dy) {
      const int wi = (dy*3 + dx)*1024 + (nt*16 + col)*32 + quad*8;
      short8 bh = *(const short8*)&w2h[wi];
      short8 bl = *(const short8*)&w2l[wi];
      #pragma unroll
      for (int y = 0; y < 4; ++y) {
        const int idx = ((yh*4 + y + dy)*18 + col + dx)*40 + quad*8;
        short8 ah = *(const short8*)&smu[idx];
        short8 al = *(const short8*)&smu[7200 + idx];
        acc2[y] = __builtin_amdgcn_mfma_f32_16x16x32_bf16(ah, bh, acc2[y], 0, 0, 0);
        acc2[y] = __builtin_amdgcn_mfma_f32_16x16x32_bf16(ah, bl, acc2[y], 0, 0, 0);
        acc2[y] = __builtin_amdgcn_mfma_f32_16x16x32_bf16(al, bh, acc2[y], 0, 0, 0);
      }
    }
  }

  // ---- epilogue: bn2+relu+2x2 maxpool + quadrant partial sum -> tfp ----
  {
    const int oc = nt*16 + col;                 // D: row=quad*4+reg (=x), col=oc
    const float s2 = tg2[oc]*BN_RS, bo2 = tb2[oc];
    float psum = 0.f;
    #pragma unroll
    for (int yp = 0; yp < 2; ++yp)
      #pragma unroll
      for (int i2 = 0; i2 < 2; ++i2) {
        float v00 = fmaxf(fmaf(acc2[2*yp][2*i2],     s2, bo2), 0.f);
        float v01 = fmaxf(fmaf(acc2[2*yp][2*i2+1],   s2, bo2), 0.f);
        float v10 = fmaxf(fmaf(acc2[2*yp+1][2*i2],   s2, bo2), 0.f);
        float v11 = fmaxf(fmaf(acc2[2*yp+1][2*i2+1], s2, bo2), 0.f);
        psum += fmaxf(fmaxf(v00, v01), fmaxf(v10, v11));
      }
    psum += __shfl_xor(psum, 16);
    psum += __shfl_xor(psum, 32);
    if (yh == 1 && quad == 0) smf[nt*32 + col] = psum;   // XS region is dead
    __syncthreads();
    if (yh == 0 && quad == 0) {
      float tot = psum + smf[nt*32 + col];
      tfp[b*256 + (rs*2 + ch)*32 + oc] = tot;
    }
  }
}

// ============================== gate + top2 ================================
__global__ __launch_bounds__(64) void gate_kernel(
    const float* __restrict__ tfp, const float* __restrict__ tfw, const float* __restrict__ tfb,
    const float* __restrict__ gw1, const float* __restrict__ gb1,
    const float* __restrict__ gw2, const float* __restrict__ gb2,
    float* __restrict__ outBal, int* __restrict__ tk)
{
  __shared__ float feat[128], rf[64], g1[32], bal[8];
  const int b = blockIdx.x, t = threadIdx.x;
  #pragma unroll
  for (int h = 0; h < 2; ++h) {
    const int f = t + 64*h;
    const int oc = f >> 2, qy = (f >> 1) & 1, qx = f & 1;
    feat[f] = (tfp[b*256 + (4*qy + qx)*32 + oc] +
               tfp[b*256 + (4*qy + 2 + qx)*32 + oc]) * (1.f/64.f);
  }
  __syncthreads();
  {
    float a = tfb[t];
    const float4* wp = (const float4*)&tfw[t*128];
    #pragma unroll 8
    for (int i4 = 0; i4 < 32; ++i4) {
      float4 wv = wp[i4];
      a = fmaf(wv.x, feat[4*i4], a);   a = fmaf(wv.y, feat[4*i4+1], a);
      a = fmaf(wv.z, feat[4*i4+2], a); a = fmaf(wv.w, feat[4*i4+3], a);
    }
    rf[t] = fmaxf(a, 0.f);
  }
  __syncthreads();
  if (t < 32) {
    float a = gb1[t];
    const float4* wp = (const float4*)&gw1[t*64];
    #pragma unroll
    for (int i4 = 0; i4 < 16; ++i4) {
      float4 wv = wp[i4];
      a = fmaf(wv.x, rf[4*i4], a);   a = fmaf(wv.y, rf[4*i4+1], a);
      a = fmaf(wv.z, rf[4*i4+2], a); a = fmaf(wv.w, rf[4*i4+3], a);
    }
    g1[t] = fmaxf(a, 0.f);
  }
  __syncthreads();
  if (t < 8) {
    float a = gb2[t];
    const float4* wp = (const float4*)&gw2[t*32];
    #pragma unroll
    for (int i4 = 0; i4 < 8; ++i4) {
      float4 wv = wp[i4];
      a = fmaf(wv.x, g1[4*i4], a);   a = fmaf(wv.y, g1[4*i4+1], a);
      a = fmaf(wv.z, g1[4*i4+2], a); a = fmaf(wv.w, g1[4*i4+3], a);
    }
    const float v = a - 0.25f;   // boost=0, -LOAD_PEN*usage = -0.25
    bal[t] = v;
    outBal[b*8 + t] = v;
  }
  __syncthreads();
  if (t == 0) {
    int t0 = 0; float b0 = bal[0];
    #pragma unroll
    for (int e2 = 1; e2 < 8; ++e2) if (bal[e2] > b0) { b0 = bal[e2]; t0 = e2; }
    int t1 = -1; float b1 = -3.4e38f;
    #pragma unroll
    for (int e2 = 0; e2 < 8; ++e2) if (e2 != t0 && bal[e2] > b1) { b1 = bal[e2]; t1 = e2; }
    tk[b*2] = t0; tk[b*2 + 1] = t1;
  }
}

// ========== expALL: scan + conv1 + conv2(MFMA) + conv3(MFMA) + FC ==========
// grid 256 = one block/sample, 512 thr, __launch_bounds__(512,2) (no spill,
// VGPR ~120 measured). R13/R16 body.
#define XA_IMG  0
#define XA_FEAT 3600
#define XA_SFF  3728
#define XA_SGG  3856
#define XA_XF   9040
#define XA_W1F  12508
#define XA_BN1F 13372
#define XA_SC   9040      // FC partial-sum scratch (512 f32), after conv3
__global__ __launch_bounds__(512, 2) void expALL_kernel(
    const float* __restrict__ x, const int* __restrict__ tk,
    const float* __restrict__ ew1, const float* __restrict__ eg1,
    const float* __restrict__ eb1, const ushort* __restrict__ ew2b,
    const float* __restrict__ eg2, const float* __restrict__ eb2,
    const ushort* __restrict__ ew3b, const float* __restrict__ eg3,
    const float* __restrict__ eb3, const float* __restrict__ efw,
    const float* __restrict__ efb, const float* __restrict__ cw1,
    const float* __restrict__ cb1, const float* __restrict__ cw2,
    const float* __restrict__ cb2, float* __restrict__ outF,
    float* __restrict__ outD)
{
  __shared__ __align__(16) ushort smu[27296];
  __shared__ int stk[512];
  __shared__ int sch;
  float* smf = (float*)smu;
  const int t = threadIdx.x, b = blockIdx.x;
  const int w8 = t >> 6, l = t & 63;
  const int col = l & 15, quad = l >> 4;

  // ---- 1) stage tk, then scan (t0, packed u64) || zero IMG + stage x ----
  stk[t] = tk[t];
  __syncthreads();
  if (t == 0) {
    // 8 expert loads packed 8 bits each (max load <= 208, fits u8)
    unsigned long long Lp = 0ull;
    int chv = 0;
    for (int i = 0; i <= b; ++i) {
      const int a = stk[2*i], c = stk[2*i+1];
      const int la = (int)((Lp >> (a*8)) & 0xFFull);
      const int lc = (int)((Lp >> (c*8)) & 0xFFull);
      chv = (la < 48) ? a : ((lc < 48) ? c : ((la <= lc) ? a : c));
      Lp += 1ull << (chv*8);
    }
    sch = chv;
  } else {
    uint4 z; z.x = 0; z.y = 0; z.z = 0; z.w = 0;
    for (int j = t-1; j < 1620; j += 511) ((uint4*)smu)[j] = z;
    for (int j = t-1; j < 3468; j += 511) {
      int ic = j / 1156, rem = j % 1156, p = rem / 34, cpd = rem % 34;
      int gy = p - 1, gx = cpd - 1;
      float v = 0.f;
      if (gy >= 0 && gy < 32 && gx >= 0 && gx < 32) v = x[b*3072 + ic*1024 + gy*32 + gx];
      smf[XA_XF + j] = v;
    }
  }
  __syncthreads();
  const int e = sch;
  if (t < 8) outD[b*8 + t] = (t == e) ? 1.f : 0.f;

  // ---- 2) conv2 B-fragments -> VGPRs (issued early, hide under conv1) ----
  const int ntile = w8 & 3, mhalf = w8 >> 2;   // conv2 wave mapping
  short8 w2f[9];
  {
    const int oc2 = ntile*16 + col;
    #pragma unroll
    for (int tap = 0; tap < 9; ++tap)
      w2f[tap] = *(const short8*)&ew2b[(e*9 + tap)*2048 + oc2*32 + quad*8];
  }

  // stage w1t [ic][k][oc], bn1
  for (int j = t; j < 864; j += 512) {
    int oc = j / 27, r = j % 27, ic = r / 9, k = r % 9;
    smf[XA_W1F + ic*288 + k*32 + oc] = ew1[e*864 + j];
  }
  if (t < 32) { smf[XA_BN1F + t] = eg1[e*32 + t]*BN_RS; smf[XA_BN1F + 32 + t] = eb1[e*32 + t]; }
  __syncthreads();

  // ---- 3) conv1 fp32: 16 groups x 2 oc x 32 cols; 4 slab loop -> bf16 IMG --
  {
    const int g = t >> 5, c = t & 31;        // g in 0..15 (2 oc each)
    for (int rs = 0; rs < 4; ++rs) {
      const int r0 = rs * 8;
      float acc[2][8];
      #pragma unroll
      for (int o = 0; o < 2; ++o)
        #pragma unroll
        for (int r = 0; r < 8; ++r) acc[o][r] = 0.f;
      for (int ic = 0; ic < 3; ++ic) {
        float w[2][9];
        #pragma unroll
        for (int k = 0; k < 9; ++k) {
          float2 wv = *(const float2*)&smf[XA_W1F + ic*288 + k*32 + 2*g];
          w[0][k] = wv.x; w[1][k] = wv.y;
        }
        const float* src = &smf[XA_XF + ic*1156 + r0*34 + c];
        #pragma unroll
        for (int rr = 0; rr < 10; ++rr) {
          const float i0 = src[rr*34], i1 = src[rr*34 + 1], i2 = src[rr*34 + 2];
          #pragma unroll
          for (int dr = 0; dr < 3; ++dr) {
            const int r = rr - dr;
            if (r < 0 || r > 7) continue;
            #pragma unroll
            for (int o = 0; o < 2; ++o) {
              acc[o][r] = fmaf(w[o][dr*3+0], i0, acc[o][r]);
              acc[o][r] = fmaf(w[o][dr*3+1], i1, acc[o][r]);
              acc[o][r] = fmaf(w[o][dr*3+2], i2, acc[o][r]);
            }
          }
        }
      }
      #pragma unroll
      for (int o = 0; o < 2; ++o) {
        const int oc = 2*g + o;
        const float s = smf[XA_BN1F + oc], bo = smf[XA_BN1F + 32 + oc];
        float m[4];
        #pragma unroll
        for (int pr = 0; pr < 4; ++pr) {
          float v0 = fmaxf(fmaf(acc[o][2*pr],   s, bo), 0.f);
          float v1 = fmaxf(fmaf(acc[o][2*pr+1], s, bo), 0.f);
          m[pr] = fmaxf(v0, v1);
        }
        #pragma unroll
        for (int pr = 0; pr < 4; ++pr) {
          float nb = __shfl_xor(m[pr], 1);
          m[pr] = fmaxf(m[pr], nb);
        }
        if (!(c & 1)) {
          const int pc = c >> 1;
          #pragma unroll
          for (int pr = 0; pr < 4; ++pr)
            smu[XA_IMG + ((rs*4 + pr + 1)*18 + (pc + 1))*40 + oc] = f2bf(m[pr]);
        }
      }
    }
  }
  __syncthreads();

  // ---- 4) conv3 B-fragments -> VGPRs (hide under conv2 MFMAs) ----
  const int oc3 = w8*16 + col;
  short8 w3f[9][2];
  #pragma unroll
  for (int tap = 0; tap < 9; ++tap)
    #pragma unroll
    for (int ks = 0; ks < 2; ++ks)
      w3f[tap][ks] = *(const short8*)&ew3b[(e*9 + tap)*8192 + oc3*64 + ks*32 + quad*8];

  // ---- 5) conv2 MFMA: straight-line, no barriers (B in regs) ----
  {
    floatx4 acc[8];
    #pragma unroll
    for (int mt = 0; mt < 8; ++mt)
      #pragma unroll
      for (int i = 0; i < 4; ++i) acc[mt][i] = 0.f;

    #pragma unroll
    for (int tap = 0; tap < 9; ++tap) {
      const int dy = tap / 3, dx = tap % 3;
      #pragma unroll
      for (int mtl = 0; mtl < 8; ++mtl) {
        const int mt = mhalf*8 + mtl;
        short8 afr = *(const short8*)
            &smu[XA_IMG + ((mt + dy)*18 + col + dx)*40 + quad*8];
        acc[mtl] = __builtin_amdgcn_mfma_f32_16x16x32_bf16(afr, w2f[tap], acc[mtl], 0, 0, 0);
      }
    }
    __syncthreads();   // all waves done reading IMG before P2T overlay

    // P2T borders + pooled interior (overlays dead IMG)
    {
      uint4 z; z.x = 0; z.y = 0; z.z = 0; z.w = 0;
      for (int j = t; j < 288; j += 512) {
        int slot = j >> 3, ofs = (j & 7) * 8, row, cl;
        if (slot < 10)      { row = 0; cl = slot; }
        else if (slot < 20) { row = 9; cl = slot - 10; }
        else if (slot < 28) { row = 1 + (slot - 20); cl = 0; }
        else                { row = 1 + (slot - 28); cl = 9; }
        *(uint4*)&smu[(row*10 + cl)*72 + ofs] = z;
      }
    }
    const int oc2 = ntile*16 + col;
    const float s2 = eg2[e*64 + oc2]*BN_RS, bo2 = eb2[e*64 + oc2];
    #pragma unroll
    for (int mtpl = 0; mtpl < 4; ++mtpl) {
      const int mtp = mhalf*4 + mtpl;
      float a00 = fmaxf(fmaf(acc[2*mtpl][0],   s2, bo2), 0.f);
      float a01 = fmaxf(fmaf(acc[2*mtpl][1],   s2, bo2), 0.f);
      float a02 = fmaxf(fmaf(acc[2*mtpl][2],   s2, bo2), 0.f);
      float a03 = fmaxf(fmaf(acc[2*mtpl][3],   s2, bo2), 0.f);
      float a10 = fmaxf(fmaf(acc[2*mtpl+1][0], s2, bo2), 0.f);
      float a11 = fmaxf(fmaf(acc[2*mtpl+1][1], s2, bo2), 0.f);
      float a12 = fmaxf(fmaf(acc[2*mtpl+1][2], s2, bo2), 0.f);
      float a13 = fmaxf(fmaf(acc[2*mtpl+1][3], s2, bo2), 0.f);
      float p0 = fmaxf(fmaxf(a00, a01), fmaxf(a10, a11));
      float p1 = fmaxf(fmaxf(a02, a03), fmaxf(a12, a13));
      smu[((mtp + 1)*10 + (quad*2 + 1))*72 + oc2] = f2bf(p0);
      smu[((mtp + 1)*10 + (quad*2 + 2))*72 + oc2] = f2bf(p1);
    }
  }
  __syncthreads();

  // ---- 6) prefetch FC layer-1 row into regs (hide under conv3) ----
  const int fcout = t & 127, fcpart = t >> 7;     // part 0..3
  float4 efr[8];
  {
    const float4* wp = (const float4*)&efw[e*16384 + fcout*128 + fcpart*32];
    #pragma unroll
    for (int i4 = 0; i4 < 8; ++i4) efr[i4] = wp[i4];
  }

  // ---- 7) conv3 MFMA: straight-line (B in regs, A from P2T LDS) ----
  {
    floatx4 acc[4];
    #pragma unroll
    for (int mt = 0; mt < 4; ++mt)
      #pragma unroll
      for (int i = 0; i < 4; ++i) acc[mt][i] = 0.f;

    #pragma unroll
    for (int tap = 0; tap < 9; ++tap) {
      const int dy = tap / 3, dx = tap % 3;
      #pragma unroll
      for (int ks = 0; ks < 2; ++ks) {
        #pragma unroll
        for (int mt = 0; mt < 4; ++mt) {
          const int m = mt*16 + col;
          const int y = m >> 3, xx = m & 7;
          short8 afr = *(const short8*)
              &smu[((y + dy)*10 + (xx + dx))*72 + ks*32 + quad*8];
          acc[mt] = __builtin_amdgcn_mfma_f32_16x16x32_bf16(afr, w3f[tap][ks], acc[mt], 0, 0, 0);
        }
      }
    }

    // epilogue: bn + relu + GAP -> feat in LDS
    {
      const float s = eg3[e*128 + oc3]*BN_RS, bo = eb3[e*128 + oc3];
      float gsum = 0.f;
      #pragma unroll
      for (int mt = 0; mt < 4; ++mt)
        #pragma unroll
        for (int i = 0; i < 4; ++i)
          gsum += fmaxf(fmaf(acc[mt][i], s, bo), 0.f);
      gsum += __shfl_xor(gsum, 16);
      gsum += __shfl_xor(gsum, 32);
      if (quad == 0) smf[XA_FEAT + oc3] = gsum * (1.f/64.f);
    }
  }
  __syncthreads();

  // ---- 8) FC chain, 4-way dot split via LDS scratch ----
  {
    float a = (fcpart == 0) ? efb[e*128 + fcout] : 0.f;
    #pragma unroll
    for (int i4 = 0; i4 < 8; ++i4) {
      float4 wv = efr[i4];
      const int base = XA_FEAT + fcpart*32 + 4*i4;
      a = fmaf(wv.x, smf[base], a);     a = fmaf(wv.y, smf[base + 1], a);
      a = fmaf(wv.z, smf[base + 2], a); a = fmaf(wv.w, smf[base + 3], a);
    }
    smf[XA_SC + fcpart*128 + fcout] = a;
  }
  __syncthreads();
  if (t < 128)
    smf[XA_SFF + t] = fmaxf(smf[XA_SC + t] + smf[XA_SC + 128 + t] +
                            smf[XA_SC + 256 + t] + smf[XA_SC + 384 + t], 0.f);
  __syncthreads();
  if (t < 256) {
    const int out = t & 63, part = t >> 6;      // part 0..3
    float a = (part == 0) ? cb1[e*64 + out] : 0.f;
    const float4* wp = (const float4*)&cw1[e*8192 + out*128 + part*32];
    #pragma unroll
    for (int i4 = 0; i4 < 8; ++i4) {
      float4 wv = wp[i4];
      const int base = XA_SFF + part*32 + 4*i4;
      a = fmaf(wv.x, smf[base], a);     a = fmaf(wv.y, smf[base + 1], a);
      a = fmaf(wv.z, smf[base + 2], a); a = fmaf(wv.w, smf[base + 3], a);
    }
    smf[XA_SC + part*64 + out] = a;
  }
  __syncthreads();
  if (t < 64)
    smf[XA_SGG + t] = fmaxf(smf[XA_SC + t] + smf[XA_SC + 64 + t] +
                            smf[XA_SC + 128 + t] + smf[XA_SC + 192 + t], 0.f);
  __syncthreads();
  if (t < 10) {
    float a = cb2[e*10 + t];
    const float4* wp = (const float4*)&cw2[e*640 + t*64];
    #pragma unroll
    for (int i4 = 0; i4 < 16; ++i4) {
      float4 wv = wp[i4];
      a = fmaf(wv.x, smf[XA_SGG + 4*i4],     a);
      a = fmaf(wv.y, smf[XA_SGG + 4*i4 + 1], a);
      a = fmaf(wv.z, smf[XA_SGG + 4*i4 + 2], a);
      a = fmaf(wv.w, smf[XA_SGG + 4*i4 + 3], a);
    }
    outF[b*10 + t] = a;   // routing weight is exactly 1.0 for the chosen expert
  }
}

// ================================ host =====================================
extern "C" void kernel_launch(void* const* d_in, const int* in_sizes, int n_in,
                              void* d_out, int out_size, void* d_ws, size_t ws_size,
                              hipStream_t stream)
{
  const float* x   = (const float*)d_in[0];
  const float* tw1 = (const float*)d_in[1];
  const float* tg1 = (const float*)d_in[2];
  const float* tb1 = (const float*)d_in[3];
  const float* tw2 = (const float*)d_in[4];
  const float* tg2 = (const float*)d_in[5];
  const float* tb2 = (const float*)d_in[6];
  const float* tfw = (const float*)d_in[7];
  const float* tfb = (const float*)d_in[8];
  const float* gw1 = (const float*)d_in[9];
  const float* gb1 = (const float*)d_in[10];
  const float* gw2 = (const float*)d_in[11];
  const float* gb2 = (const float*)d_in[12];
  const float* ew1 = (const float*)d_in[13];
  const float* eg1 = (const float*)d_in[14];
  const float* eb1 = (const float*)d_in[15];
  const float* ew2 = (const float*)d_in[16];
  const float* eg2 = (const float*)d_in[17];
  const float* eb2 = (const float*)d_in[18];
  const float* ew3 = (const float*)d_in[19];
  const float* eg3 = (const float*)d_in[20];
  const float* eb3 = (const float*)d_in[21];
  const float* efw = (const float*)d_in[22];
  const float* efb = (const float*)d_in[23];
  const float* cw1 = (const float*)d_in[24];
  const float* cb1 = (const float*)d_in[25];
  const float* cw2 = (const float*)d_in[26];
  const float* cb2 = (const float*)d_in[27];

  float*  out  = (float*)d_out;
  char*   ws   = (char*)d_ws;
  float*  tfp  = (float*)(ws + WS_TFP);
  int*    tk   = (int*)(ws + WS_TK);
  ushort* w2h  = (ushort*)(ws + WS_W2H);
  ushort* w2l  = (ushort*)(ws + WS_W2L);
  ushort* ew2b = (ushort*)(ws + WS_EW2B);
  ushort* ew3b = (ushort*)(ws + WS_EW3B);

  prep_kernel<<<396, 256, 0, stream>>>(tw2, ew2, ew3, w2h, w2l, ew2b, ew3b);
  trunk_kernel<<<2048, 256, 0, stream>>>(x, tw1, tg1, tb1, w2h, w2l, tg2, tb2, tfp);
  gate_kernel<<<256, 64, 0, stream>>>(tfp, tfw, tfb, gw1, gb1, gw2, gb2,
                                      out + 2560, tk);
  expALL_kernel<<<256, 512, 0, stream>>>(x, tk, ew1, eg1, eb1, ew2b, eg2, eb2,
                                         ew3b, eg3, eb3, efw, efb, cw1, cb1,
                                         cw2, cb2, out, out + 4608);
}